// Round 17
// baseline (111.875 us; speedup 1.0000x reference)
//
#include <hip/hip_runtime.h>
#include <hip/hip_bf16.h>

#define RR 257
#define RP 288
#define TT 21

typedef __attribute__((ext_vector_type(4))) float f32x4;
typedef __attribute__((ext_vector_type(8))) short bf16x8;

union Pack8 { unsigned short s[8]; uint4 v; };

__device__ __forceinline__ unsigned short f2b(float f) {
    union { float f; unsigned u; } v; v.f = f;
    unsigned r = v.u + 0x7fffu + ((v.u >> 16) & 1u);
    return (unsigned short)(r >> 16);
}

// Stage 1: p{1,2,3}[n,i,r] = concat(layer,1) @ W (r padded to 288), f32.
// 4 rows/block (288 blocks): halves W L2/TD traffic vs 2 rows (340->170 MB);
// a0..a3 independent FMA chains keep VALU at 2cy throughput.
__global__ __launch_bounds__(384) void proj_kernel(
    const float* __restrict__ l1, const float* __restrict__ l2, const float* __restrict__ l3,
    const float* __restrict__ W1, const float* __restrict__ W2, const float* __restrict__ W3,
    float* __restrict__ P1f, float* __restrict__ P2f, float* __restrict__ P3f)
{
    int bx = blockIdx.x;           // 3 streams * 4 n * 24 row-groups (4 rows each)
    int grp = bx % 24;
    int n = (bx / 24) & 3;
    int s = bx / 96;
    const float* layer = (s == 0) ? l1 : (s == 1) ? l2 : l3;
    const float* W     = (s == 0) ? W1 : (s == 1) ? W2 : W3;
    int i0 = grp * 4;

    __shared__ __attribute__((aligned(16))) float x[2048];  // 4 rows x 512
    const float4* src = (const float4*)(layer + (n * 96 + i0) * 512);
    float4* xv = (float4*)x;
    for (int idx = threadIdx.x; idx < 512; idx += 384) xv[idx] = src[idx];
    __syncthreads();

    int r = threadIdx.x;
    if (r < RP) {
        float a0 = 0.f, a1 = 0.f, a2 = 0.f, a3 = 0.f;
        if (r < RR) {
            float b = W[512 * RR + r];     // bias-ones row
            a0 = a1 = a2 = a3 = b;
            #pragma unroll 8
            for (int a = 0; a < 512; ++a) {
                float wa = W[a * RR + r];
                a0 = fmaf(x[a], wa, a0);
                a1 = fmaf(x[512 + a], wa, a1);
                a2 = fmaf(x[1024 + a], wa, a2);
                a3 = fmaf(x[1536 + a], wa, a3);
            }
        }
        float* P = (s == 0) ? P1f : (s == 1) ? P2f : P3f;
        int base = (n * 96 + i0) * RP + r;
        P[base]          = a0;
        P[base + RP]     = a1;
        P[base + 2 * RP] = a2;
        P[base + 3 * RP] = a3;
    }
}

// Stage 1.5 (fused): blocks 0..383 build A' (p1*p2); 384..551 build B (p3*wl).
// Both stored FRAGMENT-ORDERED bf16:
// Af[((n*576 + rg)*9 + ks)*512 + L*8 + e] = A'[rg*16 + (L&15)][ks*32 + (L>>4)*8 + e]
__global__ __launch_bounds__(256) void prep_kernel(
    const float* __restrict__ P1f, const float* __restrict__ P2f,
    const float* __restrict__ P3f, const float* __restrict__ Wl,
    unsigned short* __restrict__ Af, unsigned short* __restrict__ Bf)
{
    int bx = blockIdx.x;
    if (bx < 384) {
        int n = bx / 96, i = bx % 96;
        __shared__ __attribute__((aligned(16))) float p1row[RP];
        for (int r = threadIdx.x; r < RP; r += 256)
            p1row[r] = P1f[(n * 96 + i) * RP + r];
        __syncthreads();

        unsigned short* dst = Af + (size_t)(n * 576 + i * 6) * 9 * 512;
        for (int idx = threadIdx.x; idx < 3456; idx += 256) {
            int L = idx & 63;
            int rest = idx >> 6;            // 0..53
            int ks = rest % 9, rgl = rest / 9;
            int j = rgl * 16 + (L & 15);
            int k8 = ks * 32 + (L >> 4) * 8;
            const float* p2p = P2f + (n * 96 + j) * RP + k8;
            float4 b0 = *(const float4*)(p2p);
            float4 b1 = *(const float4*)(p2p + 4);
            float4 a0 = *(const float4*)(p1row + k8);
            float4 a1 = *(const float4*)(p1row + k8 + 4);
            Pack8 u;
            u.s[0] = f2b(a0.x * b0.x); u.s[1] = f2b(a0.y * b0.y);
            u.s[2] = f2b(a0.z * b0.z); u.s[3] = f2b(a0.w * b0.w);
            u.s[4] = f2b(a1.x * b1.x); u.s[5] = f2b(a1.y * b1.y);
            u.s[6] = f2b(a1.z * b1.z); u.s[7] = f2b(a1.w * b1.w);
            *(uint4*)(dst + (size_t)(rgl * 9 + ks) * 512 + L * 8) = u.v;
        }
    } else {
        int b2 = bx - 384;
        int h = b2 & 1;
        int t = (b2 >> 1) % TT, n = b2 / (2 * TT);
        __shared__ __attribute__((aligned(16))) float wl_lds[RP];
        for (int r = threadIdx.x; r < RP; r += 256)
            wl_lds[r] = (r < RR) ? Wl[r * TT + t] : 0.f;
        __syncthreads();

        unsigned short* dst = Bf + (size_t)(n * TT + t) * 6 * 9 * 512;
        for (int idx2 = threadIdx.x; idx2 < 1728; idx2 += 256) {
            int idx = h * 1728 + idx2;
            int L = idx & 63;
            int rest = idx >> 6;
            int ks = rest % 9, kg = rest / 9;
            int col = kg * 16 + (L & 15);
            int r8 = ks * 32 + (L >> 4) * 8;
            const float* p3p = P3f + (n * 96 + col) * RP + r8;
            float4 p0 = *(const float4*)(p3p);
            float4 p1 = *(const float4*)(p3p + 4);
            float4 w0 = *(const float4*)(wl_lds + r8);
            float4 w1 = *(const float4*)(wl_lds + r8 + 4);
            Pack8 u;
            u.s[0] = f2b(p0.x * w0.x); u.s[1] = f2b(p0.y * w0.y);
            u.s[2] = f2b(p0.z * w0.z); u.s[3] = f2b(p0.w * w0.w);
            u.s[4] = f2b(p1.x * w1.x); u.s[5] = f2b(p1.y * w1.y);
            u.s[6] = f2b(p1.z * w1.z); u.s[7] = f2b(p1.w * w1.w);
            *(uint4*)(dst + (size_t)(kg * 9 + ks) * 512 + L * 8) = u.v;
        }
    }
}

#define LOADA(s, kss) { _Pragma("unroll") for (int mf = 0; mf < 4; ++mf) \
    fa[s][mf] = *(const bf16x8*)(abase + (mf * 9 + (kss)) * 512); }
#define LOADB(s, kss) { _Pragma("unroll") for (int nf = 0; nf < 6; ++nf) \
    fb[s][nf] = *(const bf16x8*)(bbase + (nf * 9 + (kss)) * 512); }
#define MFMAS(s) { _Pragma("unroll") for (int mf = 0; mf < 4; ++mf) { \
    _Pragma("unroll") for (int nf = 0; nf < 6; ++nf) \
      acc[mf][nf] = __builtin_amdgcn_mfma_f32_16x16x32_bf16(fb[s][nf], fa[s][mf], acc[mf][nf], 0, 0, 0); } }

// Stage 2: identical to round-16 tri16 (best known): one wave/block, 64x96 tile,
// 3-deep rotating prefetch of both operands, LDS-transpose epilogue, full-line
// NT stores, bijective XCD swizzle with t fastest, s_sleep phase stagger.
__global__ __launch_bounds__(64, 2) void tri17_kernel(
    const unsigned short* __restrict__ Af, const unsigned short* __restrict__ Bf,
    float* __restrict__ out)
{
    int orig = blockIdx.x;
    if (orig < 2048) {
        int key = ((orig >> 3) ^ (orig >> 8)) & 7;
        for (int d = 0; d < key; ++d) __builtin_amdgcn_s_sleep(16);
    }
    // 12096 = 8 XCDs * 1512; bijective chunked swizzle; t fastest (A-slab L2 reuse).
    int bx = (orig & 7) * 1512 + (orig >> 3);
    int t = bx % TT;
    int mtn = bx / TT;             // 0..575
    int mt = mtn % 144;
    int n = mtn / 144;

    int lane = threadIdx.x & 63;

    const unsigned short* abase =
        Af + (size_t)(n * 576 + mt * 4) * 9 * 512 + lane * 8;
    const unsigned short* bbase =
        Bf + (size_t)(n * TT + t) * 27648 + lane * 8;

    f32x4 acc[4][6] = {};
    bf16x8 fa[3][4], fb[3][6];

    // 3-deep pipeline: prologue fills slots 0,1; steady state loads ks+2.
    LOADA(0, 0); LOADB(0, 0);
    LOADA(1, 1); LOADB(1, 1);

    LOADA(2, 2); LOADB(2, 2); MFMAS(0);   // ks=0
    LOADA(0, 3); LOADB(0, 3); MFMAS(1);   // ks=1
    LOADA(1, 4); LOADB(1, 4); MFMAS(2);   // ks=2
    LOADA(2, 5); LOADB(2, 5); MFMAS(0);   // ks=3
    LOADA(0, 6); LOADB(0, 6); MFMAS(1);   // ks=4
    LOADA(1, 7); LOADB(1, 7); MFMAS(2);   // ks=5
    LOADA(2, 8); LOADB(2, 8); MFMAS(0);   // ks=6
    MFMAS(1);                              // ks=7
    MFMAS(2);                              // ks=8

    // Epilogue: per-wave LDS transpose (pitch 100, conflict-free b128), then
    // contiguous f32x4 NT stores (1 KB/instruction = 8 full 128B lines).
    __shared__ __attribute__((aligned(16))) float tb[1600];
    int Llo = lane & 15, Lhi = lane >> 4;
    size_t outbase = ((size_t)(n * TT + t) * 9216 + mt * 64) * 96;

    #pragma unroll
    for (int mf = 0; mf < 4; ++mf) {
        #pragma unroll
        for (int nf = 0; nf < 6; ++nf)
            *(f32x4*)&tb[Llo * 100 + nf * 16 + Lhi * 4] = acc[mf][nf];
        float* gdst = out + outbase + (size_t)mf * 16 * 96;
        #pragma unroll
        for (int q = 0; q < 6; ++q) {
            int fidx = q * 64 + lane;
            int ml = fidx / 24, k4 = fidx % 24;
            f32x4 vv = *(const f32x4*)&tb[ml * 100 + k4 * 4];
            __builtin_nontemporal_store(vv, (f32x4*)(gdst + (size_t)fidx * 4));
        }
    }
}

extern "C" void kernel_launch(void* const* d_in, const int* in_sizes, int n_in,
                              void* d_out, int out_size, void* d_ws, size_t ws_size,
                              hipStream_t stream) {
    const float* l1 = (const float*)d_in[0];
    const float* l2 = (const float*)d_in[1];
    const float* l3 = (const float*)d_in[2];
    const float* W1 = (const float*)d_in[3];
    const float* W2 = (const float*)d_in[4];
    const float* W3 = (const float*)d_in[5];
    const float* Wl = (const float*)d_in[6];

    float* P1f = (float*)d_ws;                 // 3 x 384*288 f32
    float* P2f = P1f + 384 * RP;
    float* P3f = P2f + 384 * RP;
    unsigned short* Af = (unsigned short*)(P3f + 384 * RP);  // 4*576*9*512 bf16 = 21.2 MB
    unsigned short* Bf = Af + (size_t)4 * 576 * 9 * 512;     // 4*21*6*9*512 bf16 = 4.65 MB

    proj_kernel<<<288, 384, 0, stream>>>(l1, l2, l3, W1, W2, W3, P1f, P2f, P3f);
    prep_kernel<<<552, 256, 0, stream>>>(P1f, P2f, P3f, Wl, Af, Bf);
    tri17_kernel<<<12096, 64, 0, stream>>>(Af, Bf, (float*)d_out);
}